// Round 9
// baseline (131.202 us; speedup 1.0000x reference)
//
#include <hip/hip_runtime.h>
#include <hip/hip_bf16.h>

// out[b,m,n] = sum_k fq(x1)[b,m,k] * fq(x2)[b,k,n], B=8 M=4096 K=64 N=4096.
// fq maps every value to code/255, code in [0,255] -> codes exact in bf16.
// kernel1 (merged): quantize A (straight) + B (transposed -> [n][k]) once.
// kernel2: persistent-row GEMM. Block = 32 m-rows x ALL 4096 n, looping 32
// chunks of 128 cols. Software pipeline per iter: P1 {store R(i-1) || stage
// Bs(i)} bar P2 {MFMA(i) + repack->R} bar. A-frags preloaded to regs once.
// Targets store-issue phase bubbles (write-bound: 512MB f32 ~76us floor).

#define BATCH 8
#define MDIM 4096
#define KDIM 64
#define NDIM 4096

typedef __attribute__((ext_vector_type(4))) unsigned short u16x4;
typedef __attribute__((ext_vector_type(8))) short s16x8;
typedef __attribute__((ext_vector_type(4))) float f32x4;

// quantize x -> integer code (0..level-1) as bf16 bit pattern (exact:
// integers 0..255 have zero low-mantissa bits in f32)
__device__ __forceinline__ unsigned short qcode(float x, float c, float inv) {
    float xc = fminf(fmaxf(x, 0.0f), c);
    float k = rintf(xc * inv);            // round-half-even == np.round
    return (unsigned short)(__float_as_uint(k) >> 16);
}

// ---- kernel 1: quantize A [B,M,K]->codes (same layout), and B [B,K,N] ->
// codes transposed [B,N,K]. Block-range dispatch.
#define QA_BLOCKS 2048   // 2M f32 elems / (256 thr * 4 elems)

__global__ void quant_both(const float* __restrict__ x1, const float* __restrict__ x2,
                           unsigned short* __restrict__ qA, unsigned short* __restrict__ qBt,
                           const float* __restrict__ c1p, const float* __restrict__ c2p,
                           const int* __restrict__ lvp) {
    __shared__ unsigned short T[64 * 68];   // B path only; pad 68 spreads banks
    const int t = threadIdx.x;
    const float lvm1 = (float)(lvp[0] - 1);

    if (blockIdx.x < QA_BLOCKS) {
        const float c = c1p[0], inv = lvm1 / c;
        int i = blockIdx.x * 256 + t;
        float4 v = ((const float4*)x1)[i];
        u16x4 o;
        o[0] = qcode(v.x, c, inv);
        o[1] = qcode(v.y, c, inv);
        o[2] = qcode(v.z, c, inv);
        o[3] = qcode(v.w, c, inv);
        ((u16x4*)qA)[i] = o;
        return;
    }

    const float c = c2p[0], inv = lvm1 / c;
    int bi = blockIdx.x - QA_BLOCKS;        // [0, 512)
    int b = bi >> 6;                        // batch
    int n0 = (bi & 63) * 64;                // n tile origin

    const float* src = x2 + (size_t)b * KDIM * NDIM + n0;
#pragma unroll
    for (int it = 0; it < 4; ++it) {
        int qi = t + it * 256;
        int k = qi >> 4, c4 = qi & 15;      // 64 rows x 16 float4
        float4 v = *(const float4*)(src + (size_t)k * NDIM + c4 * 4);
        u16x4 o;
        o[0] = qcode(v.x, c, inv);
        o[1] = qcode(v.y, c, inv);
        o[2] = qcode(v.z, c, inv);
        o[3] = qcode(v.w, c, inv);
        *(u16x4*)&T[k * 68 + c4 * 4] = o;
    }
    __syncthreads();

    unsigned short* dst = qBt + ((size_t)b * NDIM + n0) * KDIM;
#pragma unroll
    for (int it = 0; it < 4; ++it) {
        int qi = t + it * 256;
        int n = qi >> 4, c4 = qi & 15;      // 64 out-rows x 16 chunks of 4 k
        u16x4 o;
        o[0] = T[(c4 * 4 + 0) * 68 + n];
        o[1] = T[(c4 * 4 + 1) * 68 + n];
        o[2] = T[(c4 * 4 + 2) * 68 + n];
        o[3] = T[(c4 * 4 + 3) * 68 + n];
        *(u16x4*)(dst + (size_t)n * KDIM + c4 * 4) = o;
    }
}

// ---- kernel 2: persistent-row pipelined GEMM.
// Block (mt,b): rows [mt*32, mt*32+32), all N. 32 iters of 128-col chunks
// (start chunk staggered by mt). 4 waves split each chunk's N by 32.
__global__ __launch_bounds__(256)
void gemm_q(const unsigned short* __restrict__ qA, const unsigned short* __restrict__ qBt,
            const float* __restrict__ c1p, const float* __restrict__ c2p,
            const int* __restrict__ lvp, float* __restrict__ out) {
    __shared__ __align__(16) unsigned char smem[36864];
    unsigned short* As = (unsigned short*)smem;             // [32][64], 4KB
    unsigned short* Bs = (unsigned short*)(smem + 4096);    // [128][64], 16KB
    float* R = (float*)(smem + 20480);                      // [32][128], 16KB

    const int mt = blockIdx.x, b = blockIdx.y;
    const int t = threadIdx.x;
    const int lane = t & 63, w = t >> 6;
    const int r16 = lane & 15, kq = lane >> 4;

    const float c1 = c1p[0], c2 = c2p[0];
    const float lvm1 = (float)(lvp[0] - 1);
    const float s = (c1 / lvm1) * (c2 / lvm1);
    const size_t obase = (size_t)b * MDIM * NDIM;
    const unsigned short* gBbase = qBt + (size_t)b * NDIM * KDIM;

    // ---- prologue: stage As (once) + Bs(chunk i0)
    {
        int row = t >> 3, c8 = t & 7;
        s16x8 va = *(const s16x8*)(qA + ((size_t)b * MDIM + mt * 32 + row) * KDIM + c8 * 8);
        int off = (row * 128 + c8 * 16) ^ ((row & 7) << 4);
        *(s16x8*)((char*)As + off) = va;
    }
    const int i0 = mt & 31;
#define STAGE_B(ic)                                                            \
    {                                                                          \
        const unsigned short* gB = gBbase + (size_t)(ic) * 128 * KDIM;         \
        _Pragma("unroll")                                                      \
        for (int it = 0; it < 4; ++it) {                                       \
            int qi = t + it * 256;                                             \
            int row = qi >> 3, c8 = qi & 7;                                    \
            s16x8 vb = *(const s16x8*)(gB + (size_t)row * KDIM + c8 * 8);      \
            int off = (row * 128 + c8 * 16) ^ ((row & 7) << 4);                \
            *(s16x8*)((char*)Bs + off) = vb;                                   \
        }                                                                      \
    }
    STAGE_B(i0);
    __syncthreads();

    // preload A fragments to registers (As dead afterwards)
    s16x8 afrag[2][2];
#pragma unroll
    for (int mf = 0; mf < 2; ++mf)
#pragma unroll
        for (int ks = 0; ks < 2; ++ks) {
            int row = mf * 16 + r16;
            int off = (row * 128 + ks * 64 + kq * 16) ^ ((row & 7) << 4);
            afrag[mf][ks] = *(const s16x8*)((const char*)As + off);
        }

#define MFMA_REPACK()                                                          \
    {                                                                          \
        f32x4 acc[2][2] = {};                                                  \
        _Pragma("unroll")                                                      \
        for (int ks = 0; ks < 2; ++ks) {                                       \
            const int kb = ks * 64 + kq * 16;                                  \
            s16x8 bf[2];                                                       \
            _Pragma("unroll")                                                  \
            for (int nf = 0; nf < 2; ++nf) {                                   \
                int row = w * 32 + nf * 16 + r16;                              \
                int off = (row * 128 + kb) ^ ((row & 7) << 4);                 \
                bf[nf] = *(const s16x8*)((const char*)Bs + off);               \
            }                                                                  \
            _Pragma("unroll")                                                  \
            for (int mf = 0; mf < 2; ++mf)                                     \
                _Pragma("unroll")                                              \
                for (int nf = 0; nf < 2; ++nf)                                 \
                    acc[mf][nf] = __builtin_amdgcn_mfma_f32_16x16x32_bf16(     \
                        afrag[mf][ks], bf[nf], acc[mf][nf], 0, 0, 0);          \
        }                                                                      \
        _Pragma("unroll")                                                      \
        for (int mf = 0; mf < 2; ++mf)                                         \
            _Pragma("unroll")                                                  \
            for (int nf = 0; nf < 2; ++nf) {                                   \
                int col = w * 32 + nf * 16 + r16;                              \
                _Pragma("unroll")                                              \
                for (int ii = 0; ii < 4; ++ii) {                               \
                    int lr = mf * 16 + kq * 4 + ii;                            \
                    int byte = (lr * 512 + col * 4) ^ ((lr & 7) << 4);         \
                    *(float*)((char*)R + byte) = acc[mf][nf][ii] * s;          \
                }                                                              \
            }                                                                  \
    }

#define STORE_R(ic)                                                            \
    {                                                                          \
        _Pragma("unroll")                                                      \
        for (int k2 = 0; k2 < 4; ++k2) {                                       \
            int lr = w * 8 + k2 * 2 + (lane >> 5);                             \
            int byte = (lr * 512 + (lane & 31) * 16) ^ ((lr & 7) << 4);        \
            f32x4 v = *(const f32x4*)((const char*)R + byte);                  \
            float* dst = out + obase + (size_t)(mt * 32 + lr) * NDIM           \
                       + (ic) * 128 + (lane & 31) * 4;                         \
            *(f32x4*)dst = v;                                                  \
        }                                                                      \
    }

    // ---- iter 0 compute
    MFMA_REPACK();
    __syncthreads();

    // ---- main pipeline: P1 {store R(prev) || stage Bs(cur)} bar P2 {MFMA}
    for (int j = 1; j < 32; ++j) {
        const int ic = (mt + j) & 31;
        const int ip = (mt + j - 1) & 31;
        STORE_R(ip);
        STAGE_B(ic);
        __syncthreads();
        MFMA_REPACK();
        __syncthreads();
    }
    STORE_R((mt + 31) & 31);
#undef STAGE_B
#undef MFMA_REPACK
#undef STORE_R
}

extern "C" void kernel_launch(void* const* d_in, const int* in_sizes, int n_in,
                              void* d_out, int out_size, void* d_ws, size_t ws_size,
                              hipStream_t stream) {
    const float* x1 = (const float*)d_in[0];
    const float* x2 = (const float*)d_in[1];
    const float* c1 = (const float*)d_in[2];
    const float* c2 = (const float*)d_in[3];
    const int* lv   = (const int*)d_in[4];
    float* out = (float*)d_out;

    // workspace: qA codes 4MB @ 0, qB^T codes 4MB @ +4MB (needs ws >= 8MB)
    unsigned short* qA = (unsigned short*)d_ws;
    unsigned short* qB = qA + (size_t)BATCH * MDIM * KDIM;

    quant_both<<<QA_BLOCKS + BATCH * (NDIM / 64), 256, 0, stream>>>(
        x1, x2, qA, qB, c1, c2, lv);
    gemm_q<<<dim3(MDIM / 32, BATCH), 256, 0, stream>>>(
        qA, qB, c1, c2, lv, out);
}

// Round 10
// 110.044 us; speedup vs baseline: 1.1923x; 1.1923x over previous
//
#include <hip/hip_runtime.h>
#include <hip/hip_bf16.h>

// out[b,m,n] = sum_k fq(x1)[b,m,k] * fq(x2)[b,k,n], B=8 M=4096 K=64 N=4096.
// fq maps every value to code/255, code in [0,255] -> codes exact in bf16.
// kernel1 (merged): quantize A (straight) + B (transposed -> [n][k]) once.
// kernel2 (r8 structure): LDS-staged 64x256 MFMA GEMM; staging now uses
// global_load_lds width=16 with PRE-SWIZZLED global source (linear LDS dest,
// chunk = (l&7)^(row&7) — same involution as the swizzled read). Epilogue
// repacks acc through LDS -> full 1KB-row dwordx4 stores.
// Write-bound: 512MB f32 out ~76us floor at 6.7TB/s measured fill BW.

#define BATCH 8
#define MDIM 4096
#define KDIM 64
#define NDIM 4096

typedef __attribute__((ext_vector_type(4))) unsigned short u16x4;
typedef __attribute__((ext_vector_type(8))) short s16x8;
typedef __attribute__((ext_vector_type(4))) float f32x4;

// async global->LDS, 16B per lane, LDS dest = wave-uniform base + lane*16
#define GLOAD_LDS16(gsrc, ldst)                                               \
    __builtin_amdgcn_global_load_lds(                                         \
        (const __attribute__((address_space(1))) void*)(gsrc),                \
        (__attribute__((address_space(3))) void*)(ldst), 16, 0, 0)

// quantize x -> integer code (0..level-1) as bf16 bit pattern (exact:
// integers 0..255 have zero low-mantissa bits in f32)
__device__ __forceinline__ unsigned short qcode(float x, float c, float inv) {
    float xc = fminf(fmaxf(x, 0.0f), c);
    float k = rintf(xc * inv);            // round-half-even == np.round
    return (unsigned short)(__float_as_uint(k) >> 16);
}

// ---- kernel 1: quantize A [B,M,K]->codes (same layout), and B [B,K,N] ->
// codes transposed [B,N,K]. Block-range dispatch: first QA_BLOCKS blocks do
// A (pure elementwise), the rest do 64x64 B tiles through LDS.
#define QA_BLOCKS 2048   // 2M f32 elems / (256 thr * 4 elems)

__global__ void quant_both(const float* __restrict__ x1, const float* __restrict__ x2,
                           unsigned short* __restrict__ qA, unsigned short* __restrict__ qBt,
                           const float* __restrict__ c1p, const float* __restrict__ c2p,
                           const int* __restrict__ lvp) {
    __shared__ unsigned short T[64 * 68];   // B path only; pad 68 spreads banks
    const int t = threadIdx.x;
    const float lvm1 = (float)(lvp[0] - 1);

    if (blockIdx.x < QA_BLOCKS) {
        // ---- A path: x1 f32 -> bf16 codes, 1 float4 per thread
        const float c = c1p[0], inv = lvm1 / c;
        int i = blockIdx.x * 256 + t;
        float4 v = ((const float4*)x1)[i];
        u16x4 o;
        o[0] = qcode(v.x, c, inv);
        o[1] = qcode(v.y, c, inv);
        o[2] = qcode(v.z, c, inv);
        o[3] = qcode(v.w, c, inv);
        ((u16x4*)qA)[i] = o;
        return;
    }

    // ---- B path: quantize + transpose one [64 k][64 n] tile
    const float c = c2p[0], inv = lvm1 / c;
    int bi = blockIdx.x - QA_BLOCKS;        // [0, 512)
    int b = bi >> 6;                        // batch
    int n0 = (bi & 63) * 64;                // n tile origin

    const float* src = x2 + (size_t)b * KDIM * NDIM + n0;
#pragma unroll
    for (int it = 0; it < 4; ++it) {
        int qi = t + it * 256;
        int k = qi >> 4, c4 = qi & 15;      // 64 rows x 16 float4
        float4 v = *(const float4*)(src + (size_t)k * NDIM + c4 * 4);
        u16x4 o;
        o[0] = qcode(v.x, c, inv);
        o[1] = qcode(v.y, c, inv);
        o[2] = qcode(v.z, c, inv);
        o[3] = qcode(v.w, c, inv);
        *(u16x4*)&T[k * 68 + c4 * 4] = o;
    }
    __syncthreads();

    unsigned short* dst = qBt + ((size_t)b * NDIM + n0) * KDIM;
#pragma unroll
    for (int it = 0; it < 4; ++it) {
        int qi = t + it * 256;
        int n = qi >> 4, c4 = qi & 15;      // 64 out-rows x 16 chunks of 4 k
        u16x4 o;
        o[0] = T[(c4 * 4 + 0) * 68 + n];
        o[1] = T[(c4 * 4 + 1) * 68 + n];
        o[2] = T[(c4 * 4 + 2) * 68 + n];
        o[3] = T[(c4 * 4 + 3) * 68 + n];
        *(u16x4*)(dst + (size_t)n * KDIM + c4 * 4) = o;
    }
}

// ---- kernel 2: GEMM. 64x256 tile, full K=64 staged once in LDS via
// global_load_lds (linear dest, pre-swizzled source). 4 waves in 1x4:
// wave w owns n-slice [w*64, w*64+64) -> 4x4 fragments of 16x16x32 bf16
// MFMA. Epilogue: repack acc through LDS (reuse Bs), 1KB-row stores.
__global__ __launch_bounds__(256)
void gemm_q(const unsigned short* __restrict__ qA, const unsigned short* __restrict__ qBt,
            const float* __restrict__ c1p, const float* __restrict__ c2p,
            const int* __restrict__ lvp, float* __restrict__ out) {
    __shared__ __align__(16) unsigned char smem[40960];
    unsigned short* As = (unsigned short*)smem;            // [64][64] codes, 8KB
    unsigned short* Bs = (unsigned short*)(smem + 8192);   // [256][64] codes, 32KB
    float* R = (float*)(smem + 8192);                      // epilogue reuse, 32KB

    const int b = blockIdx.z, mt = blockIdx.y, nt = blockIdx.x;
    const int t = threadIdx.x;
    const int lane = t & 63, w = t >> 6;

    const unsigned short* gA = qA + ((size_t)b * MDIM + mt * 64) * KDIM;
    const unsigned short* gB = qBt + ((size_t)b * NDIM + nt * 256) * KDIM;

    // stage A: 64 rows x 128B. Lane l of wave w, iter it handles
    // row = it*32 + w*8 + (l>>3), within-row 16B slot (l&7) [linear LDS].
    // Source chunk pre-swizzled: chunk = (l&7) ^ (row&7), so that the
    // swizzled read (off ^ ((row&7)<<4)) sees B[row][k] in place.
#pragma unroll
    for (int it = 0; it < 2; ++it) {
        int row = it * 32 + w * 8 + (lane >> 3);
        int chunk = (lane & 7) ^ (row & 7);
        GLOAD_LDS16(gA + (size_t)row * KDIM + chunk * 8,
                    As + (it * 32 + w * 8) * 64);
    }
    // stage B: 256 rows x 128B, same scheme
#pragma unroll
    for (int it = 0; it < 8; ++it) {
        int row = it * 32 + w * 8 + (lane >> 3);
        int chunk = (lane & 7) ^ (row & 7);
        GLOAD_LDS16(gB + (size_t)row * KDIM + chunk * 8,
                    Bs + (it * 32 + w * 8) * 64);
    }
    __syncthreads();

    const int r16 = lane & 15, kq = lane >> 4;

    f32x4 acc[4][4] = {};
#pragma unroll
    for (int ks = 0; ks < 2; ++ks) {
        const int kb = ks * 64 + kq * 16;   // byte offset of lane's k-slice
        s16x8 a[4], bf[4];
#pragma unroll
        for (int mf = 0; mf < 4; ++mf) {
            int row = mf * 16 + r16;
            int off = (row * 128 + kb) ^ ((row & 7) << 4);
            a[mf] = *(const s16x8*)((const char*)As + off);
        }
#pragma unroll
        for (int nf = 0; nf < 4; ++nf) {
            int row = w * 64 + nf * 16 + r16;
            int off = (row * 128 + kb) ^ ((row & 7) << 4);
            bf[nf] = *(const s16x8*)((const char*)Bs + off);
        }
#pragma unroll
        for (int mf = 0; mf < 4; ++mf)
#pragma unroll
            for (int nf = 0; nf < 4; ++nf)
                acc[mf][nf] = __builtin_amdgcn_mfma_f32_16x16x32_bf16(
                    a[mf], bf[nf], acc[mf][nf], 0, 0, 0);
    }
    __syncthreads();   // all LDS reads done -> safe to reuse Bs as R

    // ---- epilogue: 2 passes of 32 rows x 256 cols f32 (32KB) through R;
    // each store instr = one full row = 1024B contiguous.
    // acc[mf][nf][i]: m = mf*16 + kq*4 + i, n_rel = w*64 + nf*16 + r16.
    const float c1 = c1p[0], c2 = c2p[0];
    const float lvm1 = (float)(lvp[0] - 1);
    const float s = (c1 / lvm1) * (c2 / lvm1);
    const size_t obase = (size_t)b * MDIM * NDIM;
    const int m0blk = mt * 64, n0blk = nt * 256;

#pragma unroll
    for (int p = 0; p < 2; ++p) {
        // write: scaled acc (m in [p*32, p*32+32)) -> R, XOR-swizzled
#pragma unroll
        for (int mfp = 0; mfp < 2; ++mfp) {
            int mf = 2 * p + mfp;
#pragma unroll
            for (int nf = 0; nf < 4; ++nf) {
                int n_rel = w * 64 + nf * 16 + r16;
#pragma unroll
                for (int i = 0; i < 4; ++i) {
                    int lr = mfp * 16 + kq * 4 + i;       // [0,32)
                    int byte = (lr * 1024 + n_rel * 4) ^ ((lr & 7) << 4);
                    *(float*)((char*)R + byte) = acc[mf][nf][i] * s;
                }
            }
        }
        __syncthreads();

        // read + store: wave w owns rows [w*8, w*8+8); 1 full row per instr
#pragma unroll
        for (int j = 0; j < 8; ++j) {
            int lr = w * 8 + j;
            int byte = (lr * 1024 + lane * 16) ^ ((lr & 7) << 4);
            f32x4 v = *(const f32x4*)((const char*)R + byte);
            float* dst = out + obase + (size_t)(m0blk + p * 32 + lr) * NDIM
                       + n0blk + lane * 4;
            *(f32x4*)dst = v;
        }
        __syncthreads();   // pass-0 reads done before pass-1 overwrites
    }
}

extern "C" void kernel_launch(void* const* d_in, const int* in_sizes, int n_in,
                              void* d_out, int out_size, void* d_ws, size_t ws_size,
                              hipStream_t stream) {
    const float* x1 = (const float*)d_in[0];
    const float* x2 = (const float*)d_in[1];
    const float* c1 = (const float*)d_in[2];
    const float* c2 = (const float*)d_in[3];
    const int* lv   = (const int*)d_in[4];
    float* out = (float*)d_out;

    // workspace: qA codes 4MB @ 0, qB^T codes 4MB @ +4MB (needs ws >= 8MB)
    unsigned short* qA = (unsigned short*)d_ws;
    unsigned short* qB = qA + (size_t)BATCH * MDIM * KDIM;

    quant_both<<<QA_BLOCKS + BATCH * (NDIM / 64), 256, 0, stream>>>(
        x1, x2, qA, qB, c1, c2, lv);
    gemm_q<<<dim3(NDIM / 256, MDIM / 64, BATCH), 256, 0, stream>>>(
        qA, qB, c1, c2, lv, out);
}

// Round 11
// 107.334 us; speedup vs baseline: 1.2224x; 1.0252x over previous
//
#include <hip/hip_runtime.h>
#include <hip/hip_bf16.h>

// out[b,m,n] = sum_k fq(x1)[b,m,k] * fq(x2)[b,k,n], B=8 M=4096 K=64 N=4096.
// fq maps every value to code/255, code in [0,255] -> codes exact in bf16.
// kernel1 (merged): quantize A (straight) + B (transposed -> [n][k]) once.
// kernel2 (r8 structure): LDS-staged 64x256 MFMA GEMM, repack epilogue with
// full 1KB-row dwordx4 stores. ALL block barriers are raw s_barrier with
// lgkmcnt(0)-only waits (no vmcnt drain): output stores are never forced to
// complete mid-kernel, so the write stream drains asynchronously.
// Write-bound: 512MB f32 out ~76us floor at 6.7TB/s measured fill BW.

#define BATCH 8
#define MDIM 4096
#define KDIM 64
#define NDIM 4096

typedef __attribute__((ext_vector_type(4))) unsigned short u16x4;
typedef __attribute__((ext_vector_type(8))) short s16x8;
typedef __attribute__((ext_vector_type(4))) float f32x4;

// Raw workgroup barrier: waits LDS ops only (lgkmcnt), NOT global stores.
// "memory" clobber orders all memory ops across it at compile time;
// sched_barrier(0) stops register-only ops (MFMA) hoisting past (rule #18).
#define BAR()                                                                 \
    do {                                                                      \
        asm volatile("s_waitcnt lgkmcnt(0)\n\ts_barrier" ::: "memory");       \
        __builtin_amdgcn_sched_barrier(0);                                    \
    } while (0)

// quantize x -> integer code (0..level-1) as bf16 bit pattern (exact:
// integers 0..255 have zero low-mantissa bits in f32)
__device__ __forceinline__ unsigned short qcode(float x, float c, float inv) {
    float xc = fminf(fmaxf(x, 0.0f), c);
    float k = rintf(xc * inv);            // round-half-even == np.round
    return (unsigned short)(__float_as_uint(k) >> 16);
}

// ---- kernel 1: quantize A [B,M,K]->codes (same layout), and B [B,K,N] ->
// codes transposed [B,N,K]. Block-range dispatch: first QA_BLOCKS blocks do
// A (pure elementwise), the rest do 64x64 B tiles through LDS.
#define QA_BLOCKS 2048   // 2M f32 elems / (256 thr * 4 elems)

__global__ void quant_both(const float* __restrict__ x1, const float* __restrict__ x2,
                           unsigned short* __restrict__ qA, unsigned short* __restrict__ qBt,
                           const float* __restrict__ c1p, const float* __restrict__ c2p,
                           const int* __restrict__ lvp) {
    __shared__ unsigned short T[64 * 68];   // B path only; pad 68 spreads banks
    const int t = threadIdx.x;
    const float lvm1 = (float)(lvp[0] - 1);

    if (blockIdx.x < QA_BLOCKS) {
        // ---- A path: x1 f32 -> bf16 codes, 1 float4 per thread
        const float c = c1p[0], inv = lvm1 / c;
        int i = blockIdx.x * 256 + t;
        float4 v = ((const float4*)x1)[i];
        u16x4 o;
        o[0] = qcode(v.x, c, inv);
        o[1] = qcode(v.y, c, inv);
        o[2] = qcode(v.z, c, inv);
        o[3] = qcode(v.w, c, inv);
        ((u16x4*)qA)[i] = o;
        return;
    }

    // ---- B path: quantize + transpose one [64 k][64 n] tile
    const float c = c2p[0], inv = lvm1 / c;
    int bi = blockIdx.x - QA_BLOCKS;        // [0, 512)
    int b = bi >> 6;                        // batch
    int n0 = (bi & 63) * 64;                // n tile origin

    const float* src = x2 + (size_t)b * KDIM * NDIM + n0;
#pragma unroll
    for (int it = 0; it < 4; ++it) {
        int qi = t + it * 256;
        int k = qi >> 4, c4 = qi & 15;      // 64 rows x 16 float4
        float4 v = *(const float4*)(src + (size_t)k * NDIM + c4 * 4);
        u16x4 o;
        o[0] = qcode(v.x, c, inv);
        o[1] = qcode(v.y, c, inv);
        o[2] = qcode(v.z, c, inv);
        o[3] = qcode(v.w, c, inv);
        *(u16x4*)&T[k * 68 + c4 * 4] = o;
    }
    __syncthreads();

    unsigned short* dst = qBt + ((size_t)b * NDIM + n0) * KDIM;
#pragma unroll
    for (int it = 0; it < 4; ++it) {
        int qi = t + it * 256;
        int n = qi >> 4, c4 = qi & 15;      // 64 out-rows x 16 chunks of 4 k
        u16x4 o;
        o[0] = T[(c4 * 4 + 0) * 68 + n];
        o[1] = T[(c4 * 4 + 1) * 68 + n];
        o[2] = T[(c4 * 4 + 2) * 68 + n];
        o[3] = T[(c4 * 4 + 3) * 68 + n];
        *(u16x4*)(dst + (size_t)n * KDIM + c4 * 4) = o;
    }
}

// ---- kernel 2: GEMM. 64x256 tile, full K=64 staged once in LDS
// (XOR-swizzled). 4 waves in 1x4: wave w owns n-slice [w*64, w*64+64),
// all 64 m rows -> 4x4 fragments of 16x16x32 bf16 MFMA. Epilogue: repack
// acc through LDS (reuse Bs), store FULL 1KB rows per wave instruction.
// All barriers lgkm-only (stores never drained mid-kernel).
__global__ __launch_bounds__(256)
void gemm_q(const unsigned short* __restrict__ qA, const unsigned short* __restrict__ qBt,
            const float* __restrict__ c1p, const float* __restrict__ c2p,
            const int* __restrict__ lvp, float* __restrict__ out) {
    __shared__ __align__(16) unsigned char smem[40960];
    unsigned short* As = (unsigned short*)smem;            // [64][64] codes, 8KB
    unsigned short* Bs = (unsigned short*)(smem + 8192);   // [256][64] codes, 32KB
    float* R = (float*)(smem + 8192);                      // epilogue reuse, 32KB

    const int b = blockIdx.z, mt = blockIdx.y, nt = blockIdx.x;
    const int t = threadIdx.x;

    const unsigned short* gA = qA + ((size_t)b * MDIM + mt * 64) * KDIM;
    const unsigned short* gB = qBt + ((size_t)b * NDIM + nt * 256) * KDIM;

    // stage A: 64 rows x 128B (2 x 16B per thread), swizzled
#pragma unroll
    for (int it = 0; it < 2; ++it) {
        int qi = t + it * 256;
        int row = qi >> 3, c8 = qi & 7;
        s16x8 va = *(const s16x8*)(gA + (size_t)row * KDIM + c8 * 8);
        int off = (row * 128 + c8 * 16) ^ ((row & 7) << 4);
        *(s16x8*)((char*)As + off) = va;
    }
    // stage B: 256 rows x 128B (8 x 16B per thread), swizzled
#pragma unroll
    for (int it = 0; it < 8; ++it) {
        int qi = t + it * 256;
        int row = qi >> 3, c8 = qi & 7;
        s16x8 vb = *(const s16x8*)(gB + (size_t)row * KDIM + c8 * 8);
        int off = (row * 128 + c8 * 16) ^ ((row & 7) << 4);
        *(s16x8*)((char*)Bs + off) = vb;
    }
    BAR();

    const int lane = t & 63, w = t >> 6;
    const int r16 = lane & 15, kq = lane >> 4;

    f32x4 acc[4][4] = {};
#pragma unroll
    for (int ks = 0; ks < 2; ++ks) {
        const int kb = ks * 64 + kq * 16;   // byte offset of lane's k-slice
        s16x8 a[4], bf[4];
#pragma unroll
        for (int mf = 0; mf < 4; ++mf) {
            int row = mf * 16 + r16;
            int off = (row * 128 + kb) ^ ((row & 7) << 4);
            a[mf] = *(const s16x8*)((const char*)As + off);
        }
#pragma unroll
        for (int nf = 0; nf < 4; ++nf) {
            int row = w * 64 + nf * 16 + r16;
            int off = (row * 128 + kb) ^ ((row & 7) << 4);
            bf[nf] = *(const s16x8*)((const char*)Bs + off);
        }
#pragma unroll
        for (int mf = 0; mf < 4; ++mf)
#pragma unroll
            for (int nf = 0; nf < 4; ++nf)
                acc[mf][nf] = __builtin_amdgcn_mfma_f32_16x16x32_bf16(
                    a[mf], bf[nf], acc[mf][nf], 0, 0, 0);
    }
    BAR();   // all LDS reads done -> safe to reuse Bs as R

    // ---- epilogue: 2 passes of 32 rows x 256 cols f32 (32KB) through R;
    // each store instr = one full row = 1024B contiguous.
    // acc[mf][nf][i]: m = mf*16 + kq*4 + i, n_rel = w*64 + nf*16 + r16.
    const float c1 = c1p[0], c2 = c2p[0];
    const float lvm1 = (float)(lvp[0] - 1);
    const float s = (c1 / lvm1) * (c2 / lvm1);
    const size_t obase = (size_t)b * MDIM * NDIM;
    const int m0blk = mt * 64, n0blk = nt * 256;

#pragma unroll
    for (int p = 0; p < 2; ++p) {
        // write: scaled acc (m in [p*32, p*32+32)) -> R, XOR-swizzled
#pragma unroll
        for (int mfp = 0; mfp < 2; ++mfp) {
            int mf = 2 * p + mfp;
#pragma unroll
            for (int nf = 0; nf < 4; ++nf) {
                int n_rel = w * 64 + nf * 16 + r16;
#pragma unroll
                for (int i = 0; i < 4; ++i) {
                    int lr = mfp * 16 + kq * 4 + i;       // [0,32)
                    int byte = (lr * 1024 + n_rel * 4) ^ ((lr & 7) << 4);
                    *(float*)((char*)R + byte) = acc[mf][nf][i] * s;
                }
            }
        }
        BAR();

        // read + store: wave w owns rows [w*8, w*8+8); 1 full row per instr
#pragma unroll
        for (int j = 0; j < 8; ++j) {
            int lr = w * 8 + j;
            int byte = (lr * 1024 + lane * 16) ^ ((lr & 7) << 4);
            f32x4 v = *(const f32x4*)((const char*)R + byte);
            float* dst = out + obase + (size_t)(m0blk + p * 32 + lr) * NDIM
                       + n0blk + lane * 4;
            *(f32x4*)dst = v;
        }
        BAR();   // pass-0 LDS reads done before pass-1 overwrites (lgkm only;
                 // pass-0 global stores keep draining in the background)
    }
}

extern "C" void kernel_launch(void* const* d_in, const int* in_sizes, int n_in,
                              void* d_out, int out_size, void* d_ws, size_t ws_size,
                              hipStream_t stream) {
    const float* x1 = (const float*)d_in[0];
    const float* x2 = (const float*)d_in[1];
    const float* c1 = (const float*)d_in[2];
    const float* c2 = (const float*)d_in[3];
    const int* lv   = (const int*)d_in[4];
    float* out = (float*)d_out;

    // workspace: qA codes 4MB @ 0, qB^T codes 4MB @ +4MB (needs ws >= 8MB)
    unsigned short* qA = (unsigned short*)d_ws;
    unsigned short* qB = qA + (size_t)BATCH * MDIM * KDIM;

    quant_both<<<QA_BLOCKS + BATCH * (NDIM / 64), 256, 0, stream>>>(
        x1, x2, qA, qB, c1, c2, lv);
    gemm_q<<<dim3(NDIM / 256, MDIM / 64, BATCH), 256, 0, stream>>>(
        qA, qB, c1, c2, lv, out);
}